// Round 16
// baseline (39.497 us; speedup 1.0000x reference)
//
#include <hip/hip_runtime.h>
#include <math.h>
#include <stdint.h>

#define NIMG 8
#define HH 1024
#define WW 1024
#define NPIX (HH*WW)
#define PAIRS 10000
#define STRIP 4
#define NSTRIPS 256          // strips per image (rows 1..1022, 4 rows each)
#define SBLK 157             // 1-wave sample blocks per image (157*64 >= 10000)
#define SEGCAP 30000         // worst-case eq segments per image

// ws layout (floats). EVERY rendezvous word on its OWN 128B line, per-image
// lines at img*32 stride (one XCD touches each). Finish data = ballot-
// compacted eq segments (~1.2k/image) via memory-side atomics (atomicExch /
// atomicAdd(·,0)) — correctness independent of blockIdx->XCD mapping.
// [OFF_EDGE .. +2048)   per-strip squared-sobel max (plain stores, k1)
// [OFF_MDI  + img*32]   per-image maxdiff bits (uint atomicMax)
// [OFF_DONE + img*32]   per-image done counters (uint)
// [OFF_UN   + img*32]   per-image unequal-loss accum (float atomic)
// [OFF_CNT  + img*32]   per-image valid-count accum (float atomic)
// [OFF_SEGC + img*32]   per-image eq-segment counters (uint)
// [OFF_GL] [OFF_GC] [OFF_IMGD]  global accums, own lines
// byte 65536: segs ull[NIMG][SEGCAP] — packed {d2,ad} eq segments
#define OFF_EDGE 0
#define OFF_MDI  4096
#define OFF_DONE 4352
#define OFF_UN   4608
#define OFF_CNT  4864
#define OFF_SEGC 5120
#define OFF_GL   5376
#define OFF_GC   5408
#define OFF_IMGD 5440
#define ZERO_N   1376        // zero ws[4096 .. 5472)

__device__ __forceinline__ uint64_t mix64(uint64_t x){
    x += 0x9E3779B97F4A7C15ull;
    x = (x ^ (x >> 30)) * 0xBF58476D1CE4E5B9ull;
    x = (x ^ (x >> 27)) * 0x94D049BB133111EBull;
    return x ^ (x >> 31);
}

__device__ __forceinline__ float wave_reduce_max(float v){
    for (int off = 32; off; off >>= 1)
        v = fmaxf(v, __shfl_down(v, off));
    return __shfl(v, 0);
}

__device__ __forceinline__ float wave_reduce_sum(float v){
    for (int off = 32; off; off >>= 1)
        v += __shfl_down(v, off);
    return __shfl(v, 0);
}

__device__ __forceinline__ void load16(const float* __restrict__ p, float* d){
    const float4* q = (const float4*)p;
    float4 v0 = q[0], v1 = q[1], v2 = q[2], v3 = q[3];
    d[0]=v0.x; d[1]=v0.y; d[2]=v0.z; d[3]=v0.w;
    d[4]=v1.x; d[5]=v1.y; d[6]=v1.z; d[7]=v1.w;
    d[8]=v2.x; d[9]=v2.y; d[10]=v2.z; d[11]=v2.w;
    d[12]=v3.x; d[13]=v3.y; d[14]=v3.z; d[15]=v3.w;
}

// One wave owns a 1024-wide row span (16 cols/lane), rolls 3 rows in registers,
// separable sobel, cross-lane neighbors via shuffles, max of SQUARED magnitude.
// STRIP=4 (vs 8): 512 blocks -> 2 waves/SIMD for 2x latency hiding (+20% halo).
// Block 0 zeroes this launch's padded atomic slots (boundary-separated).
__global__ __launch_bounds__(256) void edgemax_kernel(const float* __restrict__ images,
                                                      float* __restrict__ ws){
    if (blockIdx.x == 0){
        for (int i = threadIdx.x; i < ZERO_N; i += 256)
            ws[OFF_MDI + i] = 0.0f;
    }

    int img  = blockIdx.x & 7;                          // XCD-pinned
    int xb   = blockIdx.x >> 3;                         // 0..63
    const float* x = images + (size_t)img * 3 * NPIX;   // channel 0
    int wv   = threadIdx.x >> 6;
    int lane = threadIdx.x & 63;
    int strip = xb * 4 + wv;                            // 0..255
    int r0 = 1 + strip * STRIP;
    int r1 = min(r0 + STRIP - 1, HH - 2);
    int c0 = lane * 16;

    float a[16], b[16], n[16];
    load16(x + (size_t)(r0-1)*WW + c0, a);
    load16(x + (size_t)r0*WW + c0, b);

    float m = 0.0f;
    for (int r = r0; r <= r1; ++r){
        load16(x + (size_t)(r+1)*WW + c0, n);
        float sx[16], dy[16];
        #pragma unroll
        for (int i = 0; i < 16; ++i){
            sx[i] = a[i] + 2.0f*b[i] + n[i];
            dy[i] = a[i] - n[i];
        }
        float sxl = __shfl_up(sx[15], 1);
        float sxr = __shfl_down(sx[0], 1);
        float dyl = __shfl_up(dy[15], 1);
        float dyr = __shfl_down(dy[0], 1);
        #pragma unroll
        for (int j = 0; j < 16; ++j){
            float sl = (j == 0)  ? sxl : sx[j-1];
            float sr = (j == 15) ? sxr : sx[j+1];
            float dl = (j == 0)  ? dyl : dy[j-1];
            float dr = (j == 15) ? dyr : dy[j+1];
            float gx = sr - sl;
            float gy = dl + 2.0f*dy[j] + dr;
            float e2 = gx*gx + gy*gy;
            int c = c0 + j;
            if (c >= 1 && c <= WW-2) m = fmaxf(m, e2);
        }
        #pragma unroll
        for (int i = 0; i < 16; ++i){ a[i] = b[i]; b[i] = n[i]; }
    }
    for (int off = 32; off; off >>= 1)
        m = fmaxf(m, __shfl_down(m, off));
    if (lane == 0)
        ws[OFF_EDGE + img * NSTRIPS + strip] = m;
}

// One rejection attempt's loaded state (loads issued eagerly, clamped).
struct AttLd {
    int r, c, rl, cl;
    float a, b, cc, d, e, f, g, h, dg, tg;
};

__device__ __forceinline__ AttLd att_issue(uint64_t u,
        const float* __restrict__ x, const float* __restrict__ tgt,
        const float* __restrict__ dgt){
    AttLd s;
    uint32_t pix = (uint32_t)(u >> 44);                // 20-bit uniform
    s.r  = (int)(pix >> 10);
    s.c  = (int)(pix & (WW - 1));
    s.rl = min(max(s.r, 1), HH-2);
    s.cl = min(max(s.c, 1), WW-2);
    const float* p0 = x + (size_t)(s.rl-1)*WW + s.cl;
    const float* p1 = x + (size_t)s.rl*WW + s.cl;
    const float* p2 = x + (size_t)(s.rl+1)*WW + s.cl;
    s.a = p0[-1]; s.b = p0[0]; s.cc = p0[1];
    s.d = p1[-1];               s.e = p1[1];
    s.f = p2[-1]; s.g = p2[0];  s.h = p2[1];
    s.dg = dgt[s.rl*WW + s.cl];
    s.tg = tgt[s.rl*WW + s.cl];
    return s;
}

// ONE WAVE per block (64 threads): no __syncthreads/LDS in the hot path,
// straggler = E[max over 64] rejection rounds (vs 256). Sample + compacted
// eq segments; 157th-arriver block per image finishes; 8th image finisher
// writes out. Rendezvous on padded per-image lines, no fences.
__global__ __launch_bounds__(64) void sample_finish_kernel(
                               const float* __restrict__ inputs,
                               const float* __restrict__ targets,
                               const float* __restrict__ images,
                               const float* __restrict__ depth_gt,
                               float* __restrict__ ws,
                               unsigned long long* __restrict__ segs,
                               float* __restrict__ out){
    int img  = blockIdx.x & 7;                // XCD-pinned
    int jb   = blockIdx.x >> 3;               // 0..156
    int lane = threadIdx.x;                   // 0..63
    int j    = jb * 64 + lane;
    const float* x   = images   + (size_t)img * 3 * NPIX;
    const float* inp = inputs   + (size_t)img * NPIX;
    const float* tgt = targets  + (size_t)img * NPIX;
    const float* dgt = depth_gt + (size_t)img * NPIX;

    float ev = 0.0f;
    #pragma unroll
    for (int s = 0; s < 4; ++s)
        ev = fmaxf(ev, ws[OFF_EDGE + img * NSTRIPS + lane + s*64]);
    float thr2 = 0.01f * wave_reduce_max(ev);

    float mdiff = 0.0f, un = 0.0f, cntv = 0.0f;
    float d2a[3] = {0.f,0.f,0.f}, ada[3] = {0.f,0.f,0.f};
    bool  eqf[3] = {false,false,false};

    if (j < PAIRS){
        uint64_t base = ((uint64_t)(img * PAIRS + j)) << 10;
        bool pdir = (mix64(((uint64_t)(NIMG * PAIRS + img)) << 10) & 1ull) != 0ull;

        int sh = -1, sw = -1;
        float gxs = 0.f, gys = 0.f, e2s = 1.f;

        AttLd cur = att_issue(mix64(base + 0ull), x, tgt, dgt);
        for (int att = 0; att < 900; ++att){
            AttLd nxt = att_issue(mix64(base + (uint64_t)(att + 1)), x, tgt, dgt);
            float gx = (cur.cc - cur.a) + 2.0f*(cur.e - cur.d) + (cur.h - cur.f);
            float gy = (cur.a + 2.0f*cur.b + cur.cc) - (cur.f + 2.0f*cur.g + cur.h);
            float e2 = gx*gx + gy*gy;
            bool pass = (cur.r == cur.rl) && (cur.c == cur.cl) && (e2 >= thr2) &&
                        (cur.dg > -0.001f && cur.dg < 80.0f) && (cur.tg != 80.0f);
            if (pass){
                sh = cur.rl; sw = cur.cl; gxs = gx; gys = gy; e2s = e2;
                break;
            }
            cur = nxt;
        }

        if (sh >= 0){
            float inv = rsqrtf(e2s);
            float cmul = gxs * inv;
            float rmul = gys * inv;
            if (!pdir) cmul = -cmul;

            uint64_t u0 = mix64(base + 1000ull);
            uint64_t u1 = mix64(base + 1001ull);
            float dist[4];
            dist[0] = -(float)(2u + (uint32_t)(u0 & 0xFFFFFFFFull) % 29u);
            dist[1] = -(float)(2u + (uint32_t)(u0 >> 32) % 29u);
            dist[2] =  (float)(2u + (uint32_t)(u1 & 0xFFFFFFFFull) % 29u);
            dist[3] =  (float)(2u + (uint32_t)(u1 >> 32) % 29u);

            int rowc[4], colc[4];
            bool valid = true;
            #pragma unroll
            for (int k = 0; k < 4; ++k){
                int cc2 = sw + (int)rintf(dist[k] * cmul);
                int rr2 = sh + (int)rintf(dist[k] * rmul);
                if (cc2 < 0 || cc2 > WW-1 || rr2 < 0 || rr2 > HH-1) valid = false;
                colc[k] = min(max(cc2, 0), WW-1);
                rowc[k] = min(max(rr2, 0), HH-1);
            }

            if (valid){
                float t4[4], i4[4];
                #pragma unroll
                for (int k = 0; k < 4; ++k){
                    int p = rowc[k]*WW + colc[k];
                    t4[k] = tgt[p];
                    i4[k] = inp[p];
                }
                #pragma unroll
                for (int k = 0; k < 3; ++k){
                    float tA = t4[k], tB = t4[k+1];
                    float ratio = (tA + 1e-6f) / (tB + 1e-6f);
                    float adk = fabsf(tA - tB);
                    mdiff = fmaxf(mdiff, adk);
                    bool eq = (ratio < 1.03f) && (ratio > 0.9708737864077669f);
                    if (eq){
                        float d = i4[k] - i4[k+1];
                        d2a[k] = d*d; ada[k] = adk; eqf[k] = true;
                    } else {
                        float lab = (ratio >= 1.03f) ? 1.0f : -1.0f;
                        un += log1pf(expf((i4[k+1] - i4[k]) * lab));
                    }
                }
                cntv = 3.0f;
            }
        }
    }

    // ---- ballot-compact eq segments (1 counter RMW/wave; memory-side
    //      atomicExch data writes -> XCD-independent visibility) ----
    {
        unsigned long long m0 = __ballot(eqf[0]);
        unsigned long long m1 = __ballot(eqf[1]);
        unsigned long long m2 = __ballot(eqf[2]);
        int c0 = __popcll(m0), c1 = __popcll(m1), c2 = __popcll(m2);
        int wavetot = c0 + c1 + c2;
        unsigned basei = 0;
        if (lane == 0 && wavetot)
            basei = atomicAdd((unsigned int*)&ws[OFF_SEGC + img*32],
                              (unsigned)wavetot);
        basei = (unsigned)__shfl((int)basei, 0);
        unsigned long long below = (1ull << lane) - 1ull;
        unsigned long long* sp = segs + (size_t)img * SEGCAP;
        #pragma unroll
        for (int k = 0; k < 3; ++k){
            if (eqf[k]){
                unsigned off = basei
                    + (k > 0 ? (unsigned)c0 : 0u)
                    + (k > 1 ? (unsigned)c1 : 0u)
                    + (unsigned)__popcll(((k==0)?m0:(k==1)?m1:m2) & below);
                unsigned long long v = ((unsigned long long)__float_as_uint(ada[k]) << 32)
                                     | (unsigned long long)__float_as_uint(d2a[k]);
                atomicExch(&sp[off], v);
            }
        }
    }

    // ---- per-wave accumulation into padded per-image atomic lines ----
    float mdb = wave_reduce_max(mdiff);
    float unb = wave_reduce_sum(un);
    float cnb = wave_reduce_sum(cntv);
    int isLast = 0;
    if (lane == 0){
        if (mdb > 0.0f)
            atomicMax((unsigned int*)&ws[OFF_MDI + img*32], __float_as_uint(mdb));
        atomicAdd(&ws[OFF_UN  + img*32], unb);
        atomicAdd(&ws[OFF_CNT + img*32], cnb);
        asm volatile("s_waitcnt vmcnt(0)" ::: "memory");   // land before done++
        unsigned old = atomicAdd((unsigned int*)&ws[OFF_DONE + img*32], 1u);
        isLast = (old == (unsigned)(SBLK - 1)) ? 1 : 0;
    }
    isLast = __shfl(isLast, 0);

    // ---- 157th arriver: finish this image from ~10 KB compacted segs ----
    if (isLast){
        float md = __uint_as_float(
            atomicAdd((unsigned int*)&ws[OFF_MDI + img*32], 0u));
        float inv = 1.0f / (md + 1e-6f);
        unsigned nseg = atomicAdd((unsigned int*)&ws[OFF_SEGC + img*32], 0u);
        unsigned long long* sp = segs + (size_t)img * SEGCAP;

        float eqs = 0.0f;
        for (unsigned r = lane; r < nseg; r += 64){
            unsigned long long v = atomicAdd(&sp[r], 0ull);   // coherent read
            float d2v = __uint_as_float((unsigned)(v & 0xFFFFFFFFull));
            float adv = __uint_as_float((unsigned)(v >> 32));
            eqs += d2v * expf(-adv * inv);
        }
        eqs = wave_reduce_sum(eqs);

        if (lane == 0){
            float unv = atomicAdd(&ws[OFF_UN  + img*32], 0.0f);
            float cnv = atomicAdd(&ws[OFF_CNT + img*32], 0.0f);
            float Li = (eqs + unv) / fmaxf(cnv, 1.0f);   // ALPHA = 1
            atomicAdd(&ws[OFF_GL], Li);
            atomicAdd(&ws[OFF_GC], cnv);
            asm volatile("s_waitcnt vmcnt(0)" ::: "memory");
            unsigned o2 = atomicAdd((unsigned int*)&ws[OFF_IMGD], 1u);
            if (o2 == (unsigned)(NIMG - 1)){
                float gl = atomicAdd(&ws[OFF_GL], 0.0f);
                float gc = atomicAdd(&ws[OFF_GC], 0.0f);
                out[0] = gl / (float)NIMG;
                out[1] = gc / (float)NIMG;
            }
        }
    }
}

extern "C" void kernel_launch(void* const* d_in, const int* in_sizes, int n_in,
                              void* d_out, int out_size, void* d_ws, size_t ws_size,
                              hipStream_t stream) {
    const float* inputs  = (const float*)d_in[0];
    const float* targets = (const float*)d_in[1];
    const float* images  = (const float*)d_in[2];
    const float* depth   = (const float*)d_in[3];
    float* out = (float*)d_out;

    float* ws = (float*)d_ws;
    unsigned long long* segs = (unsigned long long*)((char*)d_ws + 65536);

    hipLaunchKernelGGL(edgemax_kernel, dim3(NSTRIPS/4 * NIMG), dim3(256), 0, stream,
                       images, ws);
    hipLaunchKernelGGL(sample_finish_kernel, dim3(SBLK * NIMG), dim3(64), 0, stream,
                       inputs, targets, images, depth, ws, segs, out);
}

// Round 17
// 37.096 us; speedup vs baseline: 1.0647x; 1.0647x over previous
//
#include <hip/hip_runtime.h>
#include <math.h>
#include <stdint.h>

#define NIMG 8
#define HH 1024
#define WW 1024
#define NPIX (HH*WW)
#define PAIRS 10000
#define STRIP 8
#define NSTRIPS 128          // strips per image (rows 1..1022, 8 rows each)
#define S1BLOCKS 40          // sample blocks per image
#define SEGCAP 30000         // worst-case eq segments per image (3*PAIRS)

// ws layout (floats). EVERY rendezvous word on its OWN 128B line, per-image
// lines at img*32 stride (one XCD touches each) — R11/R13 lesson. The finish
// data itself is ballot-COMPACTED eq segments (~1.2k/image, ~10 KB) written
// and read via memory-side atomics (atomicExch / atomicAdd(·,0)), so
// correctness does NOT depend on the blockIdx->XCD mapping heuristic.
// [OFF_EDGE .. +1024)   per-strip squared-sobel max (plain stores, k1;
//                       cross-kernel visibility via dispatch-boundary flush)
// [OFF_MDI  + img*32]   per-image maxdiff bits (uint atomicMax)
// [OFF_DONE + img*32]   per-image done counters (uint)
// [OFF_UN   + img*32]   per-image unequal-loss accum (float atomic)
// [OFF_CNT  + img*32]   per-image valid-count accum (float atomic)
// [OFF_SEGC + img*32]   per-image eq-segment counters (uint)
// [OFF_GL] [OFF_GC] [OFF_IMGD]  global accums, own lines
// byte 65536: segs ull[NIMG][SEGCAP] — packed {d2,ad} eq segments
#define OFF_EDGE 0
#define OFF_MDI  4096
#define OFF_DONE 4352
#define OFF_UN   4608
#define OFF_CNT  4864
#define OFF_SEGC 5120
#define OFF_GL   5376
#define OFF_GC   5408
#define OFF_IMGD 5440
#define ZERO_N   1376        // zero ws[4096 .. 5472)

__device__ __forceinline__ uint64_t mix64(uint64_t x){
    x += 0x9E3779B97F4A7C15ull;
    x = (x ^ (x >> 30)) * 0xBF58476D1CE4E5B9ull;
    x = (x ^ (x >> 27)) * 0x94D049BB133111EBull;
    return x ^ (x >> 31);
}

__device__ __forceinline__ float block_reduce_max(float v, float* sm){
    for (int off = 32; off; off >>= 1)
        v = fmaxf(v, __shfl_down(v, off));
    int wv = threadIdx.x >> 6, lane = threadIdx.x & 63;
    if (lane == 0) sm[wv] = v;
    __syncthreads();
    if (threadIdx.x == 0)
        sm[0] = fmaxf(fmaxf(sm[0], sm[1]), fmaxf(sm[2], sm[3]));
    __syncthreads();
    float r = sm[0];
    __syncthreads();
    return r;
}

__device__ __forceinline__ float block_reduce_sum(float v, float* sm){
    for (int off = 32; off; off >>= 1)
        v += __shfl_down(v, off);
    int wv = threadIdx.x >> 6, lane = threadIdx.x & 63;
    if (lane == 0) sm[wv] = v;
    __syncthreads();
    if (threadIdx.x == 0)
        sm[0] = sm[0] + sm[1] + sm[2] + sm[3];
    __syncthreads();
    float r = sm[0];
    __syncthreads();
    return r;
}

__device__ __forceinline__ void load16(const float* __restrict__ p, float* d){
    const float4* q = (const float4*)p;
    float4 v0 = q[0], v1 = q[1], v2 = q[2], v3 = q[3];
    d[0]=v0.x; d[1]=v0.y; d[2]=v0.z; d[3]=v0.w;
    d[4]=v1.x; d[5]=v1.y; d[6]=v1.z; d[7]=v1.w;
    d[8]=v2.x; d[9]=v2.y; d[10]=v2.z; d[11]=v2.w;
    d[12]=v3.x; d[13]=v3.y; d[14]=v3.z; d[15]=v3.w;
}

// One wave owns a 1024-wide row span (16 cols/lane), rolls 3 rows in registers,
// separable sobel, cross-lane neighbors via shuffles, max of SQUARED magnitude.
// Block 0 zeroes this launch's padded atomic slots (boundary-separated).
__global__ __launch_bounds__(256) void edgemax_kernel(const float* __restrict__ images,
                                                      float* __restrict__ ws){
    if (blockIdx.x == 0){
        for (int i = threadIdx.x; i < ZERO_N; i += 256)
            ws[OFF_MDI + i] = 0.0f;
    }

    int img  = blockIdx.x & 7;                          // XCD-pinned
    int xb   = blockIdx.x >> 3;                         // 0..31
    const float* x = images + (size_t)img * 3 * NPIX;   // channel 0
    int wv   = threadIdx.x >> 6;
    int lane = threadIdx.x & 63;
    int strip = xb * 4 + wv;                            // 0..127
    int r0 = 1 + strip * STRIP;
    int r1 = min(r0 + STRIP - 1, HH - 2);
    int c0 = lane * 16;

    float a[16], b[16], n[16];
    load16(x + (size_t)(r0-1)*WW + c0, a);
    load16(x + (size_t)r0*WW + c0, b);

    float m = 0.0f;
    for (int r = r0; r <= r1; ++r){
        load16(x + (size_t)(r+1)*WW + c0, n);
        float sx[16], dy[16];
        #pragma unroll
        for (int i = 0; i < 16; ++i){
            sx[i] = a[i] + 2.0f*b[i] + n[i];
            dy[i] = a[i] - n[i];
        }
        float sxl = __shfl_up(sx[15], 1);
        float sxr = __shfl_down(sx[0], 1);
        float dyl = __shfl_up(dy[15], 1);
        float dyr = __shfl_down(dy[0], 1);
        #pragma unroll
        for (int j = 0; j < 16; ++j){
            float sl = (j == 0)  ? sxl : sx[j-1];
            float sr = (j == 15) ? sxr : sx[j+1];
            float dl = (j == 0)  ? dyl : dy[j-1];
            float dr = (j == 15) ? dyr : dy[j+1];
            float gx = sr - sl;
            float gy = dl + 2.0f*dy[j] + dr;
            float e2 = gx*gx + gy*gy;
            int c = c0 + j;
            if (c >= 1 && c <= WW-2) m = fmaxf(m, e2);
        }
        #pragma unroll
        for (int i = 0; i < 16; ++i){ a[i] = b[i]; b[i] = n[i]; }
    }
    for (int off = 32; off; off >>= 1)
        m = fmaxf(m, __shfl_down(m, off));
    if (lane == 0)
        ws[OFF_EDGE + img * NSTRIPS + strip] = m;
}

// One rejection attempt's loaded state (loads issued eagerly, clamped).
struct AttLd {
    int r, c, rl, cl;
    float a, b, cc, d, e, f, g, h, dg, tg;
};

__device__ __forceinline__ AttLd att_issue(uint64_t u,
        const float* __restrict__ x, const float* __restrict__ tgt,
        const float* __restrict__ dgt){
    AttLd s;
    uint32_t pix = (uint32_t)(u >> 44);                // 20-bit uniform
    s.r  = (int)(pix >> 10);
    s.c  = (int)(pix & (WW - 1));
    s.rl = min(max(s.r, 1), HH-2);
    s.cl = min(max(s.c, 1), WW-2);
    const float* p0 = x + (size_t)(s.rl-1)*WW + s.cl;
    const float* p1 = x + (size_t)s.rl*WW + s.cl;
    const float* p2 = x + (size_t)(s.rl+1)*WW + s.cl;
    s.a = p0[-1]; s.b = p0[0]; s.cc = p0[1];
    s.d = p1[-1];               s.e = p1[1];
    s.f = p2[-1]; s.g = p2[0];  s.h = p2[1];
    s.dg = dgt[s.rl*WW + s.cl];
    s.tg = tgt[s.rl*WW + s.cl];
    return s;
}

// Sample (1 thread/pair, pipelined serial rejection) + ballot-compacted
// eq segments (memory-side atomics); 40th-arriver block per image finishes
// from the ~10 KB compacted stream; 8th image finisher writes out.
__global__ __launch_bounds__(256) void sample_finish_kernel(
                               const float* __restrict__ inputs,
                               const float* __restrict__ targets,
                               const float* __restrict__ images,
                               const float* __restrict__ depth_gt,
                               float* __restrict__ ws,
                               unsigned long long* __restrict__ segs,
                               float* __restrict__ out){
    __shared__ float sred[4];
    __shared__ unsigned flag1;
    int img  = blockIdx.x & 7;                // XCD-pinned
    int jb   = blockIdx.x >> 3;               // 0..39
    int tid  = threadIdx.x;
    int lane = tid & 63;
    int j    = jb * 256 + tid;
    const float* x   = images   + (size_t)img * 3 * NPIX;
    const float* inp = inputs   + (size_t)img * NPIX;
    const float* tgt = targets  + (size_t)img * NPIX;
    const float* dgt = depth_gt + (size_t)img * NPIX;

    float ev = 0.0f;
    if (tid < NSTRIPS) ev = ws[OFF_EDGE + img * NSTRIPS + tid];
    float thr2 = 0.01f * block_reduce_max(ev, sred);

    float mdiff = 0.0f, un = 0.0f, cntv = 0.0f;
    float d2a[3] = {0.f,0.f,0.f}, ada[3] = {0.f,0.f,0.f};
    bool  eqf[3] = {false,false,false};

    if (j < PAIRS){
        uint64_t base = ((uint64_t)(img * PAIRS + j)) << 10;
        bool pdir = (mix64(((uint64_t)(NIMG * PAIRS + img)) << 10) & 1ull) != 0ull;

        int sh = -1, sw = -1;
        float gxs = 0.f, gys = 0.f, e2s = 1.f;

        AttLd cur = att_issue(mix64(base + 0ull), x, tgt, dgt);
        for (int att = 0; att < 900; ++att){
            AttLd nxt = att_issue(mix64(base + (uint64_t)(att + 1)), x, tgt, dgt);
            float gx = (cur.cc - cur.a) + 2.0f*(cur.e - cur.d) + (cur.h - cur.f);
            float gy = (cur.a + 2.0f*cur.b + cur.cc) - (cur.f + 2.0f*cur.g + cur.h);
            float e2 = gx*gx + gy*gy;
            bool pass = (cur.r == cur.rl) && (cur.c == cur.cl) && (e2 >= thr2) &&
                        (cur.dg > -0.001f && cur.dg < 80.0f) && (cur.tg != 80.0f);
            if (pass){
                sh = cur.rl; sw = cur.cl; gxs = gx; gys = gy; e2s = e2;
                break;
            }
            cur = nxt;
        }

        if (sh >= 0){
            float inv = rsqrtf(e2s);
            float cmul = gxs * inv;
            float rmul = gys * inv;
            if (!pdir) cmul = -cmul;

            uint64_t u0 = mix64(base + 1000ull);
            uint64_t u1 = mix64(base + 1001ull);
            float dist[4];
            dist[0] = -(float)(2u + (uint32_t)(u0 & 0xFFFFFFFFull) % 29u);
            dist[1] = -(float)(2u + (uint32_t)(u0 >> 32) % 29u);
            dist[2] =  (float)(2u + (uint32_t)(u1 & 0xFFFFFFFFull) % 29u);
            dist[3] =  (float)(2u + (uint32_t)(u1 >> 32) % 29u);

            int rowc[4], colc[4];
            bool valid = true;
            #pragma unroll
            for (int k = 0; k < 4; ++k){
                int cc2 = sw + (int)rintf(dist[k] * cmul);
                int rr2 = sh + (int)rintf(dist[k] * rmul);
                if (cc2 < 0 || cc2 > WW-1 || rr2 < 0 || rr2 > HH-1) valid = false;
                colc[k] = min(max(cc2, 0), WW-1);
                rowc[k] = min(max(rr2, 0), HH-1);
            }

            if (valid){
                float t4[4], i4[4];
                #pragma unroll
                for (int k = 0; k < 4; ++k){
                    int p = rowc[k]*WW + colc[k];
                    t4[k] = tgt[p];
                    i4[k] = inp[p];
                }
                #pragma unroll
                for (int k = 0; k < 3; ++k){
                    float tA = t4[k], tB = t4[k+1];
                    float ratio = (tA + 1e-6f) / (tB + 1e-6f);
                    float adk = fabsf(tA - tB);
                    mdiff = fmaxf(mdiff, adk);
                    bool eq = (ratio < 1.03f) && (ratio > 0.9708737864077669f);
                    if (eq){
                        float d = i4[k] - i4[k+1];
                        d2a[k] = d*d; ada[k] = adk; eqf[k] = true;
                    } else {
                        float lab = (ratio >= 1.03f) ? 1.0f : -1.0f;
                        un += log1pf(expf((i4[k+1] - i4[k]) * lab));
                    }
                }
                cntv = 3.0f;
            }
        }
    }

    // ---- ballot-compact eq segments (1 counter RMW/wave; data via
    //      memory-side atomicExch so visibility is XCD-independent) ----
    {
        unsigned long long m0 = __ballot(eqf[0]);
        unsigned long long m1 = __ballot(eqf[1]);
        unsigned long long m2 = __ballot(eqf[2]);
        int c0 = __popcll(m0), c1 = __popcll(m1), c2 = __popcll(m2);
        int wavetot = c0 + c1 + c2;
        unsigned basei = 0;
        if (lane == 0 && wavetot)
            basei = atomicAdd((unsigned int*)&ws[OFF_SEGC + img*32],
                              (unsigned)wavetot);
        basei = (unsigned)__shfl((int)basei, 0);
        unsigned long long below = (1ull << lane) - 1ull;
        unsigned long long* sp = segs + (size_t)img * SEGCAP;
        #pragma unroll
        for (int k = 0; k < 3; ++k){
            if (eqf[k]){
                unsigned off = basei
                    + (k > 0 ? (unsigned)c0 : 0u)
                    + (k > 1 ? (unsigned)c1 : 0u)
                    + (unsigned)__popcll(((k==0)?m0:(k==1)?m1:m2) & below);
                unsigned long long v = ((unsigned long long)__float_as_uint(ada[k]) << 32)
                                     | (unsigned long long)__float_as_uint(d2a[k]);
                atomicExch(&sp[off], v);
            }
        }
    }

    // ---- per-block accumulation into padded per-image atomic lines ----
    float mdb = block_reduce_max(mdiff, sred);  // barrier drains every wave's
    float unb = block_reduce_sum(un, sred);     // vmem (incl. seg exchanges)
    float cnb = block_reduce_sum(cntv, sred);
    if (tid == 0){
        if (mdb > 0.0f)
            atomicMax((unsigned int*)&ws[OFF_MDI + img*32], __float_as_uint(mdb));
        atomicAdd(&ws[OFF_UN  + img*32], unb);
        atomicAdd(&ws[OFF_CNT + img*32], cnb);
        asm volatile("s_waitcnt vmcnt(0)" ::: "memory");   // land before done++
        unsigned old = atomicAdd((unsigned int*)&ws[OFF_DONE + img*32], 1u);
        flag1 = (old == (unsigned)(S1BLOCKS - 1)) ? 1u : 0u;
    }
    __syncthreads();

    // ---- 40th arriver: finish this image from ~10 KB compacted segs ----
    if (flag1){
        float md = __uint_as_float(
            atomicAdd((unsigned int*)&ws[OFF_MDI + img*32], 0u));
        float inv = 1.0f / (md + 1e-6f);
        unsigned nseg = atomicAdd((unsigned int*)&ws[OFF_SEGC + img*32], 0u);
        unsigned long long* sp = segs + (size_t)img * SEGCAP;

        float eqs = 0.0f;
        for (unsigned r = tid; r < nseg; r += 256){
            unsigned long long v = atomicAdd(&sp[r], 0ull);   // coherent read
            float d2v = __uint_as_float((unsigned)(v & 0xFFFFFFFFull));
            float adv = __uint_as_float((unsigned)(v >> 32));
            eqs += d2v * expf(-adv * inv);
        }
        eqs = block_reduce_sum(eqs, sred);

        if (tid == 0){
            float unv = atomicAdd(&ws[OFF_UN  + img*32], 0.0f);
            float cnv = atomicAdd(&ws[OFF_CNT + img*32], 0.0f);
            float Li = (eqs + unv) / fmaxf(cnv, 1.0f);   // ALPHA = 1
            atomicAdd(&ws[OFF_GL], Li);
            atomicAdd(&ws[OFF_GC], cnv);
            asm volatile("s_waitcnt vmcnt(0)" ::: "memory");
            unsigned o2 = atomicAdd((unsigned int*)&ws[OFF_IMGD], 1u);
            if (o2 == (unsigned)(NIMG - 1)){
                float gl = atomicAdd(&ws[OFF_GL], 0.0f);
                float gc = atomicAdd(&ws[OFF_GC], 0.0f);
                out[0] = gl / (float)NIMG;
                out[1] = gc / (float)NIMG;
            }
        }
    }
}

extern "C" void kernel_launch(void* const* d_in, const int* in_sizes, int n_in,
                              void* d_out, int out_size, void* d_ws, size_t ws_size,
                              hipStream_t stream) {
    const float* inputs  = (const float*)d_in[0];
    const float* targets = (const float*)d_in[1];
    const float* images  = (const float*)d_in[2];
    const float* depth   = (const float*)d_in[3];
    float* out = (float*)d_out;

    float* ws = (float*)d_ws;
    unsigned long long* segs = (unsigned long long*)((char*)d_ws + 65536);

    hipLaunchKernelGGL(edgemax_kernel, dim3(NSTRIPS/4 * NIMG), dim3(256), 0, stream,
                       images, ws);
    hipLaunchKernelGGL(sample_finish_kernel, dim3(S1BLOCKS * NIMG), dim3(256), 0, stream,
                       inputs, targets, images, depth, ws, segs, out);
}